// Round 9
// baseline (68771.539 us; speedup 1.0000x reference)
//
#include <hip/hip_runtime.h>

// Problem constants (B,T,S,L,D_IN,OUT,W = 256,512,256,36,8,10,256)
#define Tt   512
#define Ll   36
#define DIN  8
#define OUTd 10
#define CH   16    // steps per chunk kernel (32 kernels total)

typedef __attribute__((ext_vector_type(8))) short short8;
typedef __attribute__((ext_vector_type(4))) float f32x4;

__device__ __forceinline__ unsigned short f2bf(float f) {
    union { float f; unsigned int u; } v; v.f = f;
    unsigned int r = v.u + 0x7fffu + ((v.u >> 16) & 1u);   // RNE
    return (unsigned short)(r >> 16);
}
__device__ __forceinline__ float bf2f(unsigned short u) {
    union { unsigned int u; float f; } v; v.u = ((unsigned int)u) << 16;
    return v.f;
}
__device__ __forceinline__ float sp_f(float x) {      // jax.nn.softplus
    return fmaxf(x, 0.f) + __logf(1.f + __expf(-fabsf(x)));
}
__device__ __forceinline__ float tanh_f(float x) {
    float e = __expf(2.f * x);
    return 1.f - 2.f / (e + 1.f);
}
union U64F2 { unsigned long long u; float f[2]; unsigned short s[4]; };

// ---- agent-scope (sc1/LLC) helpers: h + barrier only. sc1 bypasses per-XCD L2 both ways,
//      so h is never L2-cached => coherent across XCDs without fences. ----
__device__ __forceinline__ unsigned long long ldg64(const void* p) {
    return __hip_atomic_load((const unsigned long long*)p, __ATOMIC_RELAXED, __HIP_MEMORY_SCOPE_AGENT);
}
__device__ __forceinline__ float ldgf(const float* p) {
    return __hip_atomic_load(p, __ATOMIC_RELAXED, __HIP_MEMORY_SCOPE_AGENT);
}
__device__ __forceinline__ void stgf(float* p, float v) {
    __hip_atomic_store(p, v, __ATOMIC_RELAXED, __HIP_MEMORY_SCOPE_AGENT);
}

__device__ __forceinline__ void cast_quad2(const float* src, unsigned short* dh,
                                           unsigned short* dl, long u) {
    f32x4 f = *(const f32x4*)(src + u * 4);
    U64F2 H, L;
#pragma unroll
    for (int q = 0; q < 4; ++q) {
        float v = f[q];
        unsigned short hi = f2bf(v);
        H.s[q] = hi;
        L.s[q] = f2bf(v - bf2f(hi));
    }
    *(unsigned long long*)(dh + u * 4) = H.u;
    *(unsigned long long*)(dl + u * 4) = L.u;
}

// ================= prep: init MLP (blk<8), W1/W2 hi/lo (8..15), W3 hi/lo (16..255) ====
__global__ __launch_bounds__(256) void prep_kernel(
    const float* __restrict__ x0,
    const float* __restrict__ iW1, const float* __restrict__ ib1,
    const float* __restrict__ iW2, const float* __restrict__ ib2,
    const float* __restrict__ iW3, const float* __restrict__ ib3,
    const float* __restrict__ vW1, const float* __restrict__ vW2,
    const float* __restrict__ vW3,
    float* __restrict__ h0,
    unsigned short* __restrict__ w1h, unsigned short* __restrict__ w1l,
    unsigned short* __restrict__ w2h, unsigned short* __restrict__ w2l,
    unsigned short* __restrict__ w3h, unsigned short* __restrict__ w3l) {
    const int tid = threadIdx.x, blk = blockIdx.x;
    if (blk < 8) {
        __shared__ float x0s[32][DIN];
        __shared__ float h1[32 * 257];
        __shared__ float h2[32 * 257];
        const int b0 = blk * 32;
        x0s[tid >> 3][tid & 7] = x0[(b0 + (tid >> 3)) * DIN + (tid & 7)];
        __syncthreads();
        const int j = tid;
        {
            float w[DIN];
#pragma unroll
            for (int k = 0; k < DIN; ++k) w[k] = iW1[j * DIN + k];
            float bias = ib1[j];
            for (int r = 0; r < 32; ++r) {
                float acc = bias;
#pragma unroll
                for (int k = 0; k < DIN; ++k) acc += x0s[r][k] * w[k];
                h1[r * 257 + j] = sp_f(acc);
            }
        }
        __syncthreads();
        {
            float bias = ib2[j];
            for (int rb = 0; rb < 4; ++rb) {
                float a8[8];
#pragma unroll
                for (int rr = 0; rr < 8; ++rr) a8[rr] = bias;
                for (int k = 0; k < 256; ++k) {
                    float wv = iW2[j * 256 + k];
#pragma unroll
                    for (int rr = 0; rr < 8; ++rr) a8[rr] += h1[(rb * 8 + rr) * 257 + k] * wv;
                }
#pragma unroll
                for (int rr = 0; rr < 8; ++rr) h2[(rb * 8 + rr) * 257 + j] = sp_f(a8[rr]);
            }
        }
        __syncthreads();
        {
            float bias = ib3[j];
            for (int rb = 0; rb < 4; ++rb) {
                float a8[8];
#pragma unroll
                for (int rr = 0; rr < 8; ++rr) a8[rr] = bias;
                for (int k = 0; k < 256; ++k) {
                    float wv = iW3[j * 256 + k];
#pragma unroll
                    for (int rr = 0; rr < 8; ++rr) a8[rr] += h2[(rb * 8 + rr) * 257 + k] * wv;
                }
#pragma unroll
                for (int rr = 0; rr < 8; ++rr)
                    h0[(b0 + rb * 8 + rr) * 256 + j] = a8[rr];
            }
        }
    } else if (blk < 16) {
        const int idx = blk - 8;                 // 0..3: W1 parts, 4..7: W2 parts
        const float* src = (idx < 4) ? vW1 : vW2;
        unsigned short* dh = (idx < 4) ? w1h : w2h;
        unsigned short* dl = (idx < 4) ? w1l : w2l;
        const int part = idx & 3;
        for (int u = part * 4096 + tid; u < (part + 1) * 4096; u += 256)
            cast_quad2(src, dh, dl, u);
    } else {
        for (long u = (long)(blk - 16) * 256 + tid; u < 589824; u += 240L * 256)
            cast_quad2(vW3, w3h, w3l, u);
    }
}

// ---- z-layer: 8 n-tiles/wave, hi/lo A (LDS) x hi/lo B (in-loop loads from L2),
//      3-MFMA emulation, softplus + hi/lo split out. No manual prefetch arrays (VGPR-safe). ----
__device__ __forceinline__ void layer8(
    const unsigned short* __restrict__ wh, const unsigned short* __restrict__ wl,
    const float* __restrict__ bias,
    const short* __restrict__ sH, const short* __restrict__ sL,
    short* __restrict__ dH, short* __restrict__ dL, int wv, int lane) {
    const int quad = lane >> 4, l15 = lane & 15;
    const int mt = wv >> 1, nb = (wv & 1) * 8;
    const f32x4 zero4 = {0.f, 0.f, 0.f, 0.f};
    f32x4 acc[8] = {zero4, zero4, zero4, zero4, zero4, zero4, zero4, zero4};
    for (int k0 = 0; k0 < 256; k0 += 32) {
        short8 ah = *(const short8*)(const void*)&sH[(mt * 16 + l15) * 264 + k0 + quad * 8];
        short8 al = *(const short8*)(const void*)&sL[(mt * 16 + l15) * 264 + k0 + quad * 8];
#pragma unroll
        for (int i = 0; i < 8; ++i) {
            int n = (nb + i) * 16 + l15;
            short8 bh = *(const short8*)(const void*)(wh + n * 256 + k0 + quad * 8);
            short8 bl = *(const short8*)(const void*)(wl + n * 256 + k0 + quad * 8);
            acc[i] = __builtin_amdgcn_mfma_f32_16x16x32_bf16(ah, bh, acc[i], 0, 0, 0);
            acc[i] = __builtin_amdgcn_mfma_f32_16x16x32_bf16(ah, bl, acc[i], 0, 0, 0);
            acc[i] = __builtin_amdgcn_mfma_f32_16x16x32_bf16(al, bh, acc[i], 0, 0, 0);
        }
    }
#pragma unroll
    for (int i = 0; i < 8; ++i) {
        int n = (nb + i) * 16 + l15;
        float b = bias[n];
#pragma unroll
        for (int r = 0; r < 4; ++r) {
            int row = mt * 16 + quad * 4 + r;
            float v = sp_f(acc[i][r] + b);
            unsigned short hi = f2bf(v);
            dH[row * 264 + n] = (short)hi;
            dL[row * 264 + n] = (short)f2bf(v - bf2f(hi));
        }
    }
}

// ================= chunk: CH steps; 256 blocks = 8 groups x 32; 1 group barrier/step ======
__global__ __launch_bounds__(256, 1) void chunk_kernel(
    float* hb0, float* hb1,
    const float* __restrict__ logsigs,
    const float* __restrict__ vb1, const float* __restrict__ vb2,
    const float* __restrict__ vb3,
    const float* __restrict__ roW, const float* __restrict__ rob,
    const unsigned short* __restrict__ w1h, const unsigned short* __restrict__ w1l,
    const unsigned short* __restrict__ w2h, const unsigned short* __restrict__ w2l,
    const unsigned short* __restrict__ w3h, const unsigned short* __restrict__ w3l,
    float* __restrict__ out, int* bar, int t0) {
    __shared__ short bufA[2][32 * 264];          // h hi/lo, later z2 hi/lo
    __shared__ float bufBf[32 * 292];            // z1 hi/lo (shorts), later ml (f32)
    __shared__ float lss[32 * 40];
    __shared__ float hrow[256];                  // readout row (fp32)

    short* const hlh = bufA[0];  short* const hll = bufA[1];
    short* const z2h = bufA[0];  short* const z2l = bufA[1];
    short* const z1h = (short*)bufBf;
    short* const z1l = z1h + 32 * 264;
    float* const ml  = bufBf;

    const int tid = threadIdx.x, blk = blockIdx.x;
    const int lane = tid & 63, wv = tid >> 6;
    const int quad = lane >> 4, l15 = lane & 15;
    const int g = blk >> 5, j = blk & 31;        // blk%8 == j%8 -> W3-slice XCD affinity
    const int b0 = g * 32;                       // group batch base
    const long n0 = (long)j * 288;               // W3 n-slice base
    const int s0 = j * 8;                        // owned s-slice (32B-aligned sector)
    const int rowR = b0 + j;                     // readout row
    int* const garr = bar + g * 128;             // group arrive counter (monotone)
    int* const grel = garr + 64;                 // group release word

    for (int t = t0; t < t0 + CH; ++t) {
        const float* hin = (t & 1) ? hb1 : hb0;
        float*       hout = (t & 1) ? hb0 : hb1;

        // ---- gather h(t) (sc1/LLC) + hi/lo split; stage hrow; stage lss ----
        for (int i = tid; i < 4096; i += 256) {
            int r = i >> 7, c = (i & 127) * 2;
            U64F2 v; v.u = ldg64(hin + (long)(b0 + r) * 256 + c);
            float f0 = v.f[0], f1 = v.f[1];
            unsigned short h0 = f2bf(f0), h1 = f2bf(f1);
            hlh[r * 264 + c]     = (short)h0;
            hll[r * 264 + c]     = (short)f2bf(f0 - bf2f(h0));
            hlh[r * 264 + c + 1] = (short)h1;
            hll[r * 264 + c + 1] = (short)f2bf(f1 - bf2f(h1));
        }
        if (tid < 128) {
            U64F2 v; v.u = ldg64(hin + (long)rowR * 256 + tid * 2);
            hrow[tid * 2] = v.f[0]; hrow[tid * 2 + 1] = v.f[1];
        }
        for (int i = tid; i < 32 * Ll; i += 256) {
            int r = i / Ll, l = i - r * Ll;
            lss[r * 40 + l] = logsigs[((long)(b0 + r) * Tt + t) * Ll + l];
        }
        __syncthreads();

        // ---- readout out[rowR, t, :] from h(t) (exact fp32) ----
        if (tid < OUTd) {
            float acc = rob[tid];
            const float* wp = roW + tid * 256;
            for (int s = 0; s < 256; s += 4) {
                f32x4 hv = *(const f32x4*)(const void*)&hrow[s];
                f32x4 w4 = *(const f32x4*)(wp + s);
                acc += hv[0] * w4[0] + hv[1] * w4[1] + hv[2] * w4[2] + hv[3] * w4[3];
            }
            out[((long)rowR * 513 + t) * OUTd + tid] = acc;
        }

        // ---- z1 = sp(h W1^T) -> bufB ----
        layer8(w1h, w1l, vb1, hlh, hll, z1h, z1l, wv, lane);
        __syncthreads();
        // ---- z2 = sp(z1 W2^T) -> bufA (h staging dead) ----
        layer8(w2h, w2l, vb2, z1h, z1l, z2h, z2l, wv, lane);
        __syncthreads();

        // ---- C: m = tanh(z2 W3^T + b3) for n-slice (9 n-tiles/wave, in-loop B loads) ----
        {
            const int mt = wv >> 1, nb = (wv & 1) * 9;
            const f32x4 zero4 = {0.f, 0.f, 0.f, 0.f};
            f32x4 acc[9];
#pragma unroll
            for (int i = 0; i < 9; ++i) acc[i] = zero4;
            for (int kk = 0; kk < 8; ++kk) {
                short8 ah = *(const short8*)(const void*)&z2h[(mt * 16 + l15) * 264 + kk * 32 + quad * 8];
                short8 al = *(const short8*)(const void*)&z2l[(mt * 16 + l15) * 264 + kk * 32 + quad * 8];
#pragma unroll
                for (int i = 0; i < 9; ++i) {
                    long n = n0 + (nb + i) * 16 + l15;
                    short8 bh = *(const short8*)(const void*)(w3h + n * 256 + kk * 32 + quad * 8);
                    short8 bl = *(const short8*)(const void*)(w3l + n * 256 + kk * 32 + quad * 8);
                    acc[i] = __builtin_amdgcn_mfma_f32_16x16x32_bf16(ah, bh, acc[i], 0, 0, 0);
                    acc[i] = __builtin_amdgcn_mfma_f32_16x16x32_bf16(ah, bl, acc[i], 0, 0, 0);
                    acc[i] = __builtin_amdgcn_mfma_f32_16x16x32_bf16(al, bh, acc[i], 0, 0, 0);
                }
            }
            __syncthreads();   // bufBf (z1) dead -> safe to write ml
#pragma unroll
            for (int i = 0; i < 9; ++i) {
                int lc = (nb + i) * 16 + l15;
                float b = vb3[n0 + lc];
#pragma unroll
                for (int r = 0; r < 4; ++r) {
                    int row = mt * 16 + quad * 4 + r;
                    ml[row * 292 + lc] = tanh_f(acc[i][r] + b);
                }
            }
        }
        __syncthreads();

        // ---- l-contraction + h(t+1) publish (exclusive col-slice, sc1) ----
        {
            int row = tid >> 3, sr = tid & 7;
            const f32x4* mp = (const f32x4*)(const void*)&ml[row * 292 + sr * 36];
            const f32x4* lp = (const f32x4*)(const void*)&lss[row * 40];
            float a = 0.f;
#pragma unroll
            for (int q = 0; q < 9; ++q) {
                f32x4 m4 = mp[q], l4 = lp[q];
                a += m4[0] * l4[0] + m4[1] * l4[1] + m4[2] * l4[2] + m4[3] * l4[3];
            }
            long gi = (long)(b0 + row) * 256 + s0 + sr;
            stgf(hout + gi, ldgf(hin + gi) + a);
        }

        // ---- group barrier (32 arrivals, monotone counters, tid0-only poll) ----
        __syncthreads();
        if (tid == 0) {
            int old = __hip_atomic_fetch_add(garr, 1, __ATOMIC_RELAXED, __HIP_MEMORY_SCOPE_AGENT);
            if (old == (t + 1) * 32 - 1)
                __hip_atomic_store(grel, t + 1, __ATOMIC_RELAXED, __HIP_MEMORY_SCOPE_AGENT);
            while (__hip_atomic_load(grel, __ATOMIC_RELAXED, __HIP_MEMORY_SCOPE_AGENT) < t + 1)
                __builtin_amdgcn_s_sleep(2);
        }
        __syncthreads();
    }
}

// ---------------- final readout: out[:, 512, :] ----------------
__global__ __launch_bounds__(256) void readout_last(
    const float* __restrict__ h, const float* __restrict__ roW,
    const float* __restrict__ rob, float* __restrict__ out) {
    const int tid = threadIdx.x;
    const int b0 = blockIdx.x * 32;
    for (int idx = tid; idx < 32 * OUTd; idx += 256) {
        int bl = idx / OUTd, o = idx - bl * OUTd;
        float acc = rob[o];
        const float* wp = roW + o * 256;
        float a = 0.f;
        for (int s = 0; s < 256; ++s) a += ldgf(h + (long)(b0 + bl) * 256 + s) * wp[s];
        out[((long)(b0 + bl) * 513 + Tt) * OUTd + o] = acc + a;
    }
}

extern "C" void kernel_launch(void* const* d_in, const int* in_sizes, int n_in,
                              void* d_out, int out_size, void* d_ws, size_t ws_size,
                              hipStream_t stream) {
    const float* x0      = (const float*)d_in[0];
    const float* logsigs = (const float*)d_in[1];
    const float* iW1 = (const float*)d_in[2];
    const float* ib1 = (const float*)d_in[3];
    const float* iW2 = (const float*)d_in[4];
    const float* ib2 = (const float*)d_in[5];
    const float* iW3 = (const float*)d_in[6];
    const float* ib3 = (const float*)d_in[7];
    const float* vW1 = (const float*)d_in[8];
    const float* vb1 = (const float*)d_in[9];
    const float* vW2 = (const float*)d_in[10];
    const float* vb2 = (const float*)d_in[11];
    const float* vW3 = (const float*)d_in[12];
    const float* vb3 = (const float*)d_in[13];
    const float* roW = (const float*)d_in[14];
    const float* rob = (const float*)d_in[15];
    float* out = (float*)d_out;

    char* p = (char*)d_ws;
    float* hb0          = (float*)p;                        // 262144 B
    float* hb1          = (float*)(p + 262144);             // 262144 B
    unsigned short* w1h = (unsigned short*)(p + 524288);    // 131072 B
    unsigned short* w1l = (unsigned short*)(p + 655360);    // 131072 B
    unsigned short* w2h = (unsigned short*)(p + 786432);    // 131072 B
    unsigned short* w2l = (unsigned short*)(p + 917504);    // 131072 B
    unsigned short* w3h = (unsigned short*)(p + 1048576);   // 4718592 B
    unsigned short* w3l = (unsigned short*)(p + 5767168);   // 4718592 B
    int* bar            = (int*)(p + 10485760);             // 4096 B

    hipMemsetAsync(bar, 0, 4096, stream);
    prep_kernel<<<dim3(256), dim3(256), 0, stream>>>(
        x0, iW1, ib1, iW2, ib2, iW3, ib3, vW1, vW2, vW3,
        hb0, w1h, w1l, w2h, w2l, w3h, w3l);

    for (int t0 = 0; t0 < Tt; t0 += CH) {
        chunk_kernel<<<dim3(256), dim3(256), 0, stream>>>(
            hb0, hb1, logsigs, vb1, vb2, vb3, roW, rob,
            w1h, w1l, w2h, w2l, w3h, w3l, out, bar, t0);
    }
    // t=511 (odd) writes hb0 -> final h in hb0
    readout_last<<<dim3(8), dim3(256), 0, stream>>>(hb0, roW, rob, out);
}